// Round 4
// baseline (223.146 us; speedup 1.0000x reference)
//
#include <hip/hip_runtime.h>
#include <math.h>

// Problem constants
#define BATCH 8
#define NN 64
#define DD 65536            // 64*32*32 feature length (contiguous per [b,n])
#define BPB 64              // blocks per batch -> grid = 512
#define NBLK (BATCH * BPB)
#define KC (DD / BPB)       // 1024 K floats per block per row (4 KB)
#define BKF 128             // K floats staged per stage
#define NSTG (KC / BKF)     // 8 stages
#define NTRI 10             // upper-triangle 16x16 tiles of the 64x64 Gram
#define PSZ (NTRI * 256)    // floats per partial (2560)

typedef float  floatx4 __attribute__((ext_vector_type(4)));
typedef __bf16 bf16x8  __attribute__((ext_vector_type(8)));

// ---------------------------------------------------------------------------
// Stage 1 v4: block-cooperative coalesced staging.
// R0-R3 evidence: all register-direct variants read 16-64 B chunks at 256 KB
// row stride -> channel/DRAM-page camping -> 0.7-1.9 TB/s regardless of MLP
// (R2 had guaranteed 16 KB/wave in flight and was SLOWEST). Fix: stage
// [64 rows][128 K] to LDS with contiguous 512 B-per-row reads (32 lanes x
// 16 B), fp32->bf16 during staging, double-buffered, XOR-swizzled
// (col ^= (row&7)<<4 on both sides -> even bank spread). Waves split the
// staged K (w*32..w*32+31): identical 10-MFMA tri-tile set, 8 K-steps/wave,
// same accumulators / cross-wave reduce / m89 store as the validated R0.
// ---------------------------------------------------------------------------
__global__ __launch_bounds__(256, 2) void gram_partial_kernel(const float* __restrict__ a,
                                                              float* __restrict__ part) {
    __shared__ __align__(16) union {
        unsigned char buf[2][64 * 256];       // 2 x 16 KB bf16 tiles
        float red[3][NTRI][64][4];            // 30 KB cross-wave reduce (aliases)
    } sh;

    const int bid = blockIdx.x;
    const int b = bid >> 6;           // / BPB
    const int c = bid & (BPB - 1);

    const int tid  = threadIdx.x;
    const int w    = tid >> 6;        // wave id 0..3 -> K-slice within stage
    const int lane = tid & 63;
    const int m    = lane & 15;
    const int q    = lane >> 4;

    // --- staging mapping: round j covers rows 8j..8j+7, 512 B each --------
    const int h  = tid >> 5;                  // 0..7: row within round
    const int cl = tid & 31;                  // 0..31: 16 B column chunk
    const float* gp = a + (size_t)b * NN * DD + (size_t)h * DD
                        + (size_t)c * KC + cl * 4;
    // LDS write: row_l = 8j + h; phys col = (cl*8) ^ ((row_l&7)<<4), row_l&7 == h
    const int wb = h * 256 + ((cl * 8) ^ (h << 4));

    // --- MFMA read: rows m+16g, logical col = w*64 + q*16, swizzle (m&7)<<4
    const int colr = ((w * 64 + q * 16) ^ ((m & 7) << 4));

    const unsigned sel = 0x07060302u;

    floatx4 acc[NTRI];
    #pragma unroll
    for (int i = 0; i < NTRI; ++i) acc[i] = (floatx4)0.0f;

    float4 L0, L1, L2, L3, L4, L5, L6, L7;

#define LOADS(s)                                                            \
    L0 = *(const float4*)(gp + (size_t)0 * 8 * DD + (s) * BKF);             \
    L1 = *(const float4*)(gp + (size_t)1 * 8 * DD + (s) * BKF);             \
    L2 = *(const float4*)(gp + (size_t)2 * 8 * DD + (s) * BKF);             \
    L3 = *(const float4*)(gp + (size_t)3 * 8 * DD + (s) * BKF);             \
    L4 = *(const float4*)(gp + (size_t)4 * 8 * DD + (s) * BKF);             \
    L5 = *(const float4*)(gp + (size_t)5 * 8 * DD + (s) * BKF);             \
    L6 = *(const float4*)(gp + (size_t)6 * 8 * DD + (s) * BKF);             \
    L7 = *(const float4*)(gp + (size_t)7 * 8 * DD + (s) * BKF);

#define PUT1(bs, j, Lj)                                                     \
    {                                                                       \
        unsigned lo_ = __builtin_amdgcn_perm(__float_as_uint(Lj.y),         \
                                             __float_as_uint(Lj.x), sel);   \
        unsigned hi_ = __builtin_amdgcn_perm(__float_as_uint(Lj.w),         \
                                             __float_as_uint(Lj.z), sel);   \
        *(uint2*)&sh.buf[bs][(j) * 2048 + wb] = make_uint2(lo_, hi_);       \
    }

#define PUTALL(bs)                                                          \
    PUT1(bs, 0, L0) PUT1(bs, 1, L1) PUT1(bs, 2, L2) PUT1(bs, 3, L3)         \
    PUT1(bs, 4, L4) PUT1(bs, 5, L5) PUT1(bs, 6, L6) PUT1(bs, 7, L7)

    // acc slots: 0:(0,0) 1:(0,1) 2:(0,2) 3:(0,3) 4:(1,1) 5:(1,2) 6:(1,3)
    //            7:(2,2) 8:(2,3) 9:(3,3)
#define COMPUTE(bs)                                                         \
    {                                                                       \
        const unsigned char* tb = sh.buf[bs];                               \
        bf16x8 f0 = *(const bf16x8*)(tb + (m     ) * 256 + colr);           \
        bf16x8 f1 = *(const bf16x8*)(tb + (m + 16) * 256 + colr);           \
        bf16x8 f2 = *(const bf16x8*)(tb + (m + 32) * 256 + colr);           \
        bf16x8 f3 = *(const bf16x8*)(tb + (m + 48) * 256 + colr);           \
        acc[0] = __builtin_amdgcn_mfma_f32_16x16x32_bf16(f0, f0, acc[0], 0, 0, 0); \
        acc[1] = __builtin_amdgcn_mfma_f32_16x16x32_bf16(f0, f1, acc[1], 0, 0, 0); \
        acc[2] = __builtin_amdgcn_mfma_f32_16x16x32_bf16(f0, f2, acc[2], 0, 0, 0); \
        acc[3] = __builtin_amdgcn_mfma_f32_16x16x32_bf16(f0, f3, acc[3], 0, 0, 0); \
        acc[4] = __builtin_amdgcn_mfma_f32_16x16x32_bf16(f1, f1, acc[4], 0, 0, 0); \
        acc[5] = __builtin_amdgcn_mfma_f32_16x16x32_bf16(f1, f2, acc[5], 0, 0, 0); \
        acc[6] = __builtin_amdgcn_mfma_f32_16x16x32_bf16(f1, f3, acc[6], 0, 0, 0); \
        acc[7] = __builtin_amdgcn_mfma_f32_16x16x32_bf16(f2, f2, acc[7], 0, 0, 0); \
        acc[8] = __builtin_amdgcn_mfma_f32_16x16x32_bf16(f2, f3, acc[8], 0, 0, 0); \
        acc[9] = __builtin_amdgcn_mfma_f32_16x16x32_bf16(f3, f3, acc[9], 0, 0, 0); \
    }

    // Prologue: stage 0 into buf0.
    LOADS(0)
    PUTALL(0)
    __syncthreads();

    #pragma unroll
    for (int s = 0; s < NSTG; ++s) {
        if (s + 1 < NSTG) { LOADS(s + 1) }
        __builtin_amdgcn_sched_barrier(0);    // pin load issue above compute
        COMPUTE(s & 1)
        if (s + 1 < NSTG) { PUTALL((s + 1) & 1) }
        __syncthreads();
    }
#undef LOADS
#undef PUT1
#undef PUTALL
#undef COMPUTE

    // Cross-wave reduce: waves 1..3 dump accs to LDS (aliases stage bufs —
    // safe: loop ended with __syncthreads); wave 0 sums + stores.
    if (w > 0) {
        #pragma unroll
        for (int t = 0; t < NTRI; ++t)
            *(floatx4*)&sh.red[w - 1][t][lane][0] = acc[t];
    }
    __syncthreads();
    if (w == 0) {
        #pragma unroll
        for (int t = 0; t < NTRI; ++t) {
            floatx4 r0 = *(const floatx4*)&sh.red[0][t][lane][0];
            floatx4 r1 = *(const floatx4*)&sh.red[1][t][lane][0];
            floatx4 r2 = *(const floatx4*)&sh.red[2][t][lane][0];
            acc[t] += (r0 + r1) + r2;
        }
        // slot t holds G[16*ib + 4q + r][16*jb + m] (m89 layout, validated)
        float* pg = part + (size_t)bid * PSZ;
        #pragma unroll
        for (int t = 0; t < NTRI; ++t) {
            float* tp = pg + t * 256 + m;
            #pragma unroll
            for (int r = 0; r < 4; ++r)
                tp[(q * 4 + r) * 16] = acc[t][r];
        }
    }
}

// ---------------------------------------------------------------------------
// Stage 1b: reduce BPB=64 tri-partials per batch -> gram[8][64*64] row-major.
// Lower triangle reconstructed by reading the transposed slot (each K-partial
// Gram is symmetric, so this is exact).
// ---------------------------------------------------------------------------
__global__ __launch_bounds__(128) void gram_reduce_kernel(const float* __restrict__ part,
                                                          float* __restrict__ gram) {
    const int gid = blockIdx.x * 128 + threadIdx.x;   // 0 .. 8*4096-1
    const int b   = gid >> 12;
    const int idx = gid & 4095;
    const int i   = idx >> 6;
    const int j   = idx & 63;
    const int ti  = i >> 4, tj = j >> 4;
    const int ib  = ti <= tj ? ti : tj;
    const int jb  = ti <= tj ? tj : ti;
    const int slot = ib * 4 - (ib * (ib - 1)) / 2 + (jb - ib);
    const int rr  = (ti <= tj) ? (i & 15) : (j & 15);
    const int cc  = (ti <= tj) ? (j & 15) : (i & 15);
    const int off = slot * 256 + rr * 16 + cc;
    const float* p = part + (size_t)b * BPB * PSZ + off;

    float s0 = 0.f, s1 = 0.f, s2 = 0.f, s3 = 0.f;
    #pragma unroll 4
    for (int c = 0; c < BPB; c += 4) {
        s0 += p[(size_t)(c + 0) * PSZ];
        s1 += p[(size_t)(c + 1) * PSZ];
        s2 += p[(size_t)(c + 2) * PSZ];
        s3 += p[(size_t)(c + 3) * PSZ];
    }
    gram[gid] = (s0 + s1) + (s2 + s3);
}

// ---------------------------------------------------------------------------
// Stage 2: per-batch CRF iterations. 8 blocks x 256 threads.
// ---------------------------------------------------------------------------
__global__ __launch_bounds__(256) void crf_kernel(const float* __restrict__ gram,
                                                  const float* __restrict__ logits,
                                                  const float* __restrict__ Wm,
                                                  float* __restrict__ out) {
    __shared__ float pp[NN][NN + 1];
    __shared__ float E[NN];
    __shared__ float nrm[NN];
    __shared__ float part[4 * NN];

    const int b  = blockIdx.x;
    const int tid = threadIdx.x;
    const int i  = tid & 63;
    const int jq = tid >> 6;
    const float* g = gram + b * NN * NN;

    if (jq == 0) nrm[i] = sqrtf(g[i * NN + i]);
    E[i] = 0.0f;
    __syncthreads();

    const float ni = nrm[i];
    for (int jj = 0; jj < 16; ++jj) {
        int j = jq * 16 + jj;
        float wsym = 0.5f * (Wm[i * NN + j] + Wm[j * NN + i]);
        pp[i][j] = g[i * NN + j] / (ni * nrm[j] + 1e-6f) * wsym;
    }
    const float li = logits[b * NN + i];
    __syncthreads();

    for (int it = 0; it < 10; ++it) {
        float acc = 0.0f;
        for (int jj = 0; jj < 16; ++jj) {
            int j = jq * 16 + jj;
            float t = li + E[j];
            float s = 1.0f / (1.0f + expf(-t));
            acc = fmaf(2.0f * s - 1.0f, pp[i][j], acc);
        }
        part[jq * NN + i] = acc;
        __syncthreads();
        if (jq == 0)
            E[i] = part[i] + part[NN + i] + part[2 * NN + i] + part[3 * NN + i];
        __syncthreads();
    }

    if (tid < 64) {
        float s = E[tid];
        for (int off = 32; off > 0; off >>= 1) s += __shfl_down(s, off);
        float meanE = __shfl(s, 0) * (1.0f / 64.0f);
        out[b * NN + tid] = logits[b * NN + tid] + meanE;
    }
}

extern "C" void kernel_launch(void* const* d_in, const int* in_sizes, int n_in,
                              void* d_out, int out_size, void* d_ws, size_t ws_size,
                              hipStream_t stream) {
    const float* a      = (const float*)d_in[0];  // [8,64,64,32,32]
    const float* logits = (const float*)d_in[1];  // [8,64]
    const float* Wm     = (const float*)d_in[2];  // [1,64,64]
    float* out  = (float*)d_out;                  // [8,64]

    float* part = (float*)d_ws;                           // [512][2560] fp32
    float* gram = part + (size_t)NBLK * PSZ;              // [8][4096]

    gram_partial_kernel<<<NBLK, 256, 0, stream>>>(a, part);
    gram_reduce_kernel<<<(BATCH * NN * NN) / 128, 128, 0, stream>>>(part, gram);
    crf_kernel<<<BATCH, 256, 0, stream>>>(gram, logits, Wm, out);
}